// Round 1
// baseline (548.875 us; speedup 1.0000x reference)
//
#include <hip/hip_runtime.h>
#include <hip/hip_bf16.h>
#include <cstdint>

#define BB 4
#define HH 8
#define LL 2048
#define DD 64
#define SK 40
#define NT 40
#define BHN (BB*HH)            // 32
#define SCALE 0.125f

// workspace layout in floats
#define WS_M    0                         // [BHN*LL]       = 65536
#define WS_SUB  (BHN*LL)                  // [BHN*64*DD]    = 131072
#define WS_CTX  (WS_SUB + BHN*64*DD)      // [BHN*NT*DD]    = 81920
#define WS_TOP  (WS_CTX + BHN*NT*DD)      // int [BHN*NT]

// ---------------- K1: M[b,h,l] = max_s(QK) - sum_s(QK)/L ----------------
// one wave per (bh,l) row; lane s (<40) computes one sampled dot.
__global__ __launch_bounds__(256) void k1_M(const float* __restrict__ Q,
                                            const float* __restrict__ K,
                                            const int* __restrict__ isamp,
                                            float* __restrict__ M) {
    int wid  = blockIdx.x * 4 + (threadIdx.x >> 6);   // = bh*LL + l
    int lane = threadIdx.x & 63;
    int bh   = wid >> 11;
    int l    = wid & (LL - 1);
    int s    = lane < SK ? lane : SK - 1;
    int idx  = isamp[l * SK + s];
    const float4* q4 = reinterpret_cast<const float4*>(Q + (size_t)wid * DD);
    const float4* k4 = reinterpret_cast<const float4*>(K + ((size_t)bh * LL + idx) * DD);
    float acc = 0.f;
#pragma unroll
    for (int j = 0; j < 16; j++) {
        float4 qv = q4[j]; float4 kv = k4[j];
        acc += qv.x * kv.x + qv.y * kv.y + qv.z * kv.z + qv.w * kv.w;
    }
    float mv = (lane < SK) ? acc : -INFINITY;
    float sv = (lane < SK) ? acc : 0.f;
#pragma unroll
    for (int off = 32; off; off >>= 1) {
        mv = fmaxf(mv, __shfl_xor(mv, off));
        sv += __shfl_xor(sv, off);
    }
    if (lane == 0) M[wid] = mv - sv * (1.0f / (float)LL);
}

// ---------------- K2: top-40 indices per (b,h) ----------------
// iterative argmax with (value desc, index asc) tie-break, matching lax.top_k set.
__global__ __launch_bounds__(256) void k2_topk(const float* __restrict__ M,
                                               int* __restrict__ Mtop) {
    __shared__ float m_lds[LL];
    __shared__ unsigned long long wbest[4];
    int bh = blockIdx.x, tid = threadIdx.x;
    for (int i = tid; i < LL; i += 256) m_lds[i] = M[bh * LL + i];
    __syncthreads();
    for (int t = 0; t < NT; t++) {
        unsigned long long best = 0ull;
        for (int i = tid; i < LL; i += 256) {
            float v = m_lds[i];
            unsigned u = __float_as_uint(v);
            u = (u & 0x80000000u) ? ~u : (u | 0x80000000u);
            unsigned long long key = ((unsigned long long)u << 32) | (unsigned)(~i);
            if (key > best) best = key;
        }
#pragma unroll
        for (int off = 32; off; off >>= 1) {
            unsigned long long o = __shfl_xor(best, off);
            if (o > best) best = o;
        }
        if ((tid & 63) == 0) wbest[tid >> 6] = best;
        __syncthreads();
        if (tid == 0) {
            unsigned long long b = wbest[0];
            for (int w = 1; w < 4; w++) if (wbest[w] > b) b = wbest[w];
            int idx = (int)(~(unsigned)(b & 0xFFFFFFFFull));
            Mtop[bh * NT + t] = idx;
            m_lds[idx] = -INFINITY;
        }
        __syncthreads();
    }
}

// ---------------- K3: masked softmax attention for each (b,h,u) ----------------
__global__ __launch_bounds__(256) void k3_attn(const float* __restrict__ Q,
                                               const float* __restrict__ K,
                                               const float* __restrict__ V,
                                               const int* __restrict__ Mtop,
                                               float* __restrict__ ctx) {
    __shared__ float q_lds[DD];
    __shared__ float s_lds[LL];
    __shared__ float red[4];
    __shared__ float wacc[4][DD];
    int bh = blockIdx.x / NT;
    int u  = blockIdx.x % NT;
    int tid = threadIdx.x;
    int qi = Mtop[bh * NT + u];
    int nv = qi + 1;                         // causal: k <= qi valid
    if (tid < 16)
        reinterpret_cast<float4*>(q_lds)[tid] =
            reinterpret_cast<const float4*>(Q + ((size_t)bh * LL + qi) * DD)[tid];
    __syncthreads();
    // scores
    for (int k = tid; k < nv; k += 256) {
        const float4* k4 = reinterpret_cast<const float4*>(K + ((size_t)bh * LL + k) * DD);
        float acc = 0.f;
#pragma unroll
        for (int j = 0; j < 16; j++) {
            float4 kv = k4[j];
            acc += q_lds[4*j+0]*kv.x + q_lds[4*j+1]*kv.y + q_lds[4*j+2]*kv.z + q_lds[4*j+3]*kv.w;
        }
        s_lds[k] = acc * SCALE;
    }
    __syncthreads();
    // max
    float lm = -INFINITY;
    for (int k = tid; k < nv; k += 256) lm = fmaxf(lm, s_lds[k]);
#pragma unroll
    for (int off = 32; off; off >>= 1) lm = fmaxf(lm, __shfl_xor(lm, off));
    if ((tid & 63) == 0) red[tid >> 6] = lm;
    __syncthreads();
    float gmax = fmaxf(fmaxf(red[0], red[1]), fmaxf(red[2], red[3]));
    __syncthreads();
    // exp + sum
    float ls = 0.f;
    for (int k = tid; k < nv; k += 256) {
        float e = __expf(s_lds[k] - gmax);
        s_lds[k] = e;
        ls += e;
    }
    __syncthreads();
#pragma unroll
    for (int off = 32; off; off >>= 1) ls += __shfl_xor(ls, off);
    if ((tid & 63) == 0) red[tid >> 6] = ls;
    __syncthreads();
    float rZ = 1.f / (red[0] + red[1] + red[2] + red[3]);
    // PV: wave w handles k = w, w+4, ...; lane owns d
    int w = tid >> 6, lane = tid & 63;
    float acc = 0.f;
    for (int k = w; k < nv; k += 4)
        acc += s_lds[k] * V[((size_t)bh * LL + k) * DD + lane];
    wacc[w][lane] = acc;
    __syncthreads();
    if (tid < DD) {
        float c = (wacc[0][tid] + wacc[1][tid] + wacc[2][tid] + wacc[3][tid]) * rZ;
        ctx[((size_t)bh * NT + u) * DD + tid] = c;
    }
}

// ---------------- K4a: 32-row sub-chunk sums of V ----------------
__global__ __launch_bounds__(64) void k4a_sub(const float* __restrict__ V,
                                              float* __restrict__ sub) {
    int blk = blockIdx.x;                 // bh*64 + j
    int lane = threadIdx.x;
    size_t base = (size_t)blk * 32 * DD + lane;
    float acc = 0.f;
#pragma unroll 8
    for (int r = 0; r < 32; r++) acc += V[base + (size_t)r * DD];
    sub[(size_t)blk * DD + lane] = acc;
}

// ---------------- K4b: prefix offset + inclusive rescan ----------------
__global__ __launch_bounds__(64) void k4b_scan(const float* __restrict__ V,
                                               const float* __restrict__ sub,
                                               float* __restrict__ out) {
    int blk = blockIdx.x;
    int bh = blk >> 6, j = blk & 63;
    int lane = threadIdx.x;
    float off = 0.f;
    for (int p = 0; p < j; p++) off += sub[((size_t)(bh * 64 + p)) * DD + lane];
    size_t base = (size_t)blk * 32 * DD + lane;
    float acc = off;
    for (int r = 0; r < 32; r++) {
        acc += V[base + (size_t)r * DD];
        out[base + (size_t)r * DD] = acc;
    }
}

// ---------------- K5: scatter ctx_update rows ----------------
__global__ __launch_bounds__(256) void k5_scatter(const int* __restrict__ Mtop,
                                                  const float* __restrict__ ctx,
                                                  float* __restrict__ out) {
    int bh = blockIdx.x, tid = threadIdx.x;
    for (int t = tid; t < NT * DD; t += 256) {
        int u = t >> 6, d = t & 63;
        int row = Mtop[bh * NT + u];
        out[((size_t)bh * LL + row) * DD + d] = ctx[((size_t)bh * NT + u) * DD + d];
    }
}

extern "C" void kernel_launch(void* const* d_in, const int* in_sizes, int n_in,
                              void* d_out, int out_size, void* d_ws, size_t ws_size,
                              hipStream_t stream) {
    const float* Q = (const float*)d_in[0];
    const float* K = (const float*)d_in[1];
    const float* V = (const float*)d_in[2];
    const int* isamp = (const int*)d_in[3];
    float* ws  = (float*)d_ws;
    float* M   = ws + WS_M;
    float* sub = ws + WS_SUB;
    float* ctx = ws + WS_CTX;
    int*   Mtop = (int*)(ws + WS_TOP);
    float* out = (float*)d_out;

    k1_M     <<<BHN * LL / 4, 256, 0, stream>>>(Q, K, isamp, M);
    k2_topk  <<<BHN,          256, 0, stream>>>(M, Mtop);
    k3_attn  <<<BHN * NT,     256, 0, stream>>>(Q, K, V, Mtop, ctx);
    k4a_sub  <<<BHN * 64,      64, 0, stream>>>(V, sub);
    k4b_scan <<<BHN * 64,      64, 0, stream>>>(V, sub, out);
    k5_scatter<<<BHN,         256, 0, stream>>>(Mtop, ctx, out);
}

// Round 3
// 304.960 us; speedup vs baseline: 1.7998x; 1.7998x over previous
//
#include <hip/hip_runtime.h>
#include <hip/hip_bf16.h>
#include <cstdint>

#define BB 4
#define HH 8
#define LL 2048
#define DD 64
#define SK 40
#define NT 40
#define BHN (BB*HH)            // 32
#define SCALE 0.125f
#define CHUNK 128
#define NCH (LL/CHUNK)         // 16

// workspace layout in floats
#define WS_M    0                          // [BHN*LL]            = 65536
#define WS_SUB  (WS_M + BHN*LL)            // [BHN*64*DD]         = 131072
#define WS_CTX  (WS_SUB + BHN*64*DD)       // [BHN*NT*DD]         = 81920
#define WS_PM   (WS_CTX + BHN*NT*DD)       // [BHN*NT*NCH]        = 20480
#define WS_PSUM (WS_PM + BHN*NT*NCH)       // [BHN*NT*NCH]        = 20480
#define WS_PACC (WS_PSUM + BHN*NT*NCH)     // [BHN*NT*NCH*DD]     = 1310720
#define WS_TOP  (WS_PACC + BHN*NT*NCH*DD)  // int [BHN*NT]

// ---------------- K1: M[b,h,l] = max_s(QK) - sum_s(QK)/L ----------------
__global__ __launch_bounds__(256) void k1_M(const float* __restrict__ Q,
                                            const float* __restrict__ K,
                                            const int* __restrict__ isamp,
                                            float* __restrict__ M) {
    int wid  = blockIdx.x * 4 + (threadIdx.x >> 6);   // = bh*LL + l
    int lane = threadIdx.x & 63;
    int bh   = wid >> 11;
    int l    = wid & (LL - 1);
    int s    = lane < SK ? lane : SK - 1;
    int idx  = isamp[l * SK + s];
    const float4* q4 = reinterpret_cast<const float4*>(Q + (size_t)wid * DD);
    const float4* k4 = reinterpret_cast<const float4*>(K + ((size_t)bh * LL + idx) * DD);
    float acc = 0.f;
#pragma unroll
    for (int j = 0; j < 16; j++) {
        float4 qv = q4[j]; float4 kv = k4[j];
        acc += qv.x * kv.x + qv.y * kv.y + qv.z * kv.z + qv.w * kv.w;
    }
    float mv = (lane < SK) ? acc : -INFINITY;
    float sv = (lane < SK) ? acc : 0.f;
#pragma unroll
    for (int off = 32; off; off >>= 1) {
        mv = fmaxf(mv, __shfl_xor(mv, off));
        sv += __shfl_xor(sv, off);
    }
    if (lane == 0) M[wid] = mv - sv * (1.0f / (float)LL);
}

// ---------------- K2: top-40 indices per (b,h), one wave per bh ----------------
__global__ __launch_bounds__(64) void k2_topk(const float* __restrict__ M,
                                              int* __restrict__ Mtop) {
    __shared__ float m_lds[LL];
    int bh = blockIdx.x, lane = threadIdx.x;
    for (int i = lane; i < LL; i += 64) m_lds[i] = M[bh * LL + i];
    __syncthreads();
    for (int t = 0; t < NT; t++) {
        unsigned long long best = 0ull;
#pragma unroll
        for (int j = 0; j < LL / 64; j++) {
            int i = lane + j * 64;
            float v = m_lds[i];
            unsigned u = __float_as_uint(v);
            u = (u & 0x80000000u) ? ~u : (u | 0x80000000u);
            unsigned long long key = ((unsigned long long)u << 32) | (unsigned)(~i);
            if (key > best) best = key;
        }
#pragma unroll
        for (int off = 32; off; off >>= 1) {
            unsigned long long o = __shfl_xor(best, off);
            if (o > best) best = o;
        }
        int idx = (int)(~(unsigned)(best & 0xFFFFFFFFull));
        if (lane == 0) {
            Mtop[bh * NT + t] = idx;
            m_lds[idx] = -INFINITY;
        }
        __syncthreads();
    }
}

// ---------------- K3a: chunked partial attention ----------------
// block = (bh, chunk); computes masked scores for all 40 u's vs CHUNK keys,
// local softmax stats + partial PV, writes (m, sum, acc[64]) per (bh,u,ch).
__global__ __launch_bounds__(256) void k3a_partial(const float* __restrict__ Q,
                                                   const float* __restrict__ K,
                                                   const float* __restrict__ V,
                                                   const int* __restrict__ Mtop,
                                                   float* __restrict__ pm,
                                                   float* __restrict__ psum,
                                                   float* __restrict__ pacc) {
    __shared__ float q_lds[NT * DD];       // 10 KB
    __shared__ float s_lds[NT][CHUNK];     // 20 KB
    __shared__ int   qi_lds[NT];
    int bh = blockIdx.x / NCH;
    int ch = blockIdx.x % NCH;
    int ck = ch * CHUNK;
    int tid = threadIdx.x;

    if (tid < NT) qi_lds[tid] = Mtop[bh * NT + tid];
    __syncthreads();
    // stage the 40 gathered Q rows (640 float4)
    for (int c = tid; c < NT * 16; c += 256) {
        int u = c >> 4, j = c & 15;
        reinterpret_cast<float4*>(q_lds)[c] =
            reinterpret_cast<const float4*>(Q + ((size_t)bh * LL + qi_lds[u]) * DD)[j];
    }
    __syncthreads();

    // scores: thread pair (half 0/1) per key; K half-row kept in registers
    int k   = ck + (tid >> 1);
    int half = tid & 1;
    const float4* krow = reinterpret_cast<const float4*>(K + ((size_t)bh * LL + k) * DD) + half * 8;
    float4 kreg[8];
#pragma unroll
    for (int j = 0; j < 8; j++) kreg[j] = krow[j];
    for (int u = 0; u < NT; u++) {
        const float4* q4 = reinterpret_cast<const float4*>(q_lds + u * DD) + half * 8;
        float d = 0.f;
#pragma unroll
        for (int j = 0; j < 8; j++) {
            float4 a = q4[j], b = kreg[j];
            d += a.x * b.x + a.y * b.y + a.z * b.z + a.w * b.w;
        }
        d += __shfl_xor(d, 1);
        float s = (k <= qi_lds[u]) ? d * SCALE : -INFINITY;
        if (half == 0) s_lds[u][k - ck] = s;
    }
    __syncthreads();

    // per-u local max + expsum; wave w owns u = w + 4*uu
    int w = tid >> 6, lane = tid & 63;
#pragma unroll
    for (int uu = 0; uu < NT / 4; uu++) {
        int u = w + uu * 4;
        float s0 = s_lds[u][lane], s1 = s_lds[u][lane + 64];
        float m = fmaxf(s0, s1);
#pragma unroll
        for (int off = 32; off; off >>= 1) m = fmaxf(m, __shfl_xor(m, off));
        float e0 = (s0 == -INFINITY) ? 0.f : __expf(s0 - m);
        float e1 = (s1 == -INFINITY) ? 0.f : __expf(s1 - m);
        s_lds[u][lane] = e0;
        s_lds[u][lane + 64] = e1;
        float sm = e0 + e1;
#pragma unroll
        for (int off = 32; off; off >>= 1) sm += __shfl_xor(sm, off);
        if (lane == 0) {
            pm  [((size_t)bh * NT + u) * NCH + ch] = m;
            psum[((size_t)bh * NT + u) * NCH + ch] = sm;
        }
    }
    __syncthreads();

    // partial PV: wave w owns u = w + 4*uu, lane = d; V streamed from global (L2)
    float acc[NT / 4] = {};
    const float* vbase = V + ((size_t)bh * LL + ck) * DD + lane;
#pragma unroll 4
    for (int kk = 0; kk < CHUNK; kk++) {
        float v = vbase[(size_t)kk * DD];
#pragma unroll
        for (int uu = 0; uu < NT / 4; uu++)
            acc[uu] += s_lds[w + uu * 4][kk] * v;
    }
#pragma unroll
    for (int uu = 0; uu < NT / 4; uu++) {
        int u = w + uu * 4;
        pacc[(((size_t)bh * NT + u) * NCH + ch) * DD + lane] = acc[uu];
    }
}

// ---------------- K3b: merge 16 chunk partials per (bh,u) ----------------
__global__ __launch_bounds__(64) void k3b_reduce(const float* __restrict__ pm,
                                                 const float* __restrict__ psum,
                                                 const float* __restrict__ pacc,
                                                 float* __restrict__ ctx) {
    int row = blockIdx.x;            // bh*NT + u
    int lane = threadIdx.x;          // = d
    float pmv[NCH];
    float m = -INFINITY;
#pragma unroll
    for (int i = 0; i < NCH; i++) {
        pmv[i] = pm[(size_t)row * NCH + i];
        m = fmaxf(m, pmv[i]);
    }
    float Z = 0.f, acc = 0.f;
#pragma unroll
    for (int i = 0; i < NCH; i++) {
        float sc = (pmv[i] == -INFINITY) ? 0.f : __expf(pmv[i] - m);
        Z   += psum[(size_t)row * NCH + i] * sc;
        acc += pacc[((size_t)row * NCH + i) * DD + lane] * sc;
    }
    ctx[(size_t)row * DD + lane] = acc / Z;
}

// ---------------- K4a: 32-row sub-chunk sums of V ----------------
__global__ __launch_bounds__(64) void k4a_sub(const float* __restrict__ V,
                                              float* __restrict__ sub) {
    int blk = blockIdx.x;                 // bh*64 + j
    int lane = threadIdx.x;
    size_t base = (size_t)blk * 32 * DD + lane;
    float acc = 0.f;
#pragma unroll 8
    for (int r = 0; r < 32; r++) acc += V[base + (size_t)r * DD];
    sub[(size_t)blk * DD + lane] = acc;
}

// ---------------- K4b: prefix offset + inclusive rescan ----------------
__global__ __launch_bounds__(64) void k4b_scan(const float* __restrict__ V,
                                               const float* __restrict__ sub,
                                               float* __restrict__ out) {
    int blk = blockIdx.x;
    int bh = blk >> 6, j = blk & 63;
    int lane = threadIdx.x;
    float off = 0.f;
    for (int p = 0; p < j; p++) off += sub[((size_t)(bh * 64 + p)) * DD + lane];
    size_t base = (size_t)blk * 32 * DD + lane;
    float acc = off;
    for (int r = 0; r < 32; r++) {
        acc += V[base + (size_t)r * DD];
        out[base + (size_t)r * DD] = acc;
    }
}

// ---------------- K5: scatter ctx_update rows ----------------
__global__ __launch_bounds__(256) void k5_scatter(const int* __restrict__ Mtop,
                                                  const float* __restrict__ ctx,
                                                  float* __restrict__ out) {
    int bh = blockIdx.x, tid = threadIdx.x;
    for (int t = tid; t < NT * DD; t += 256) {
        int u = t >> 6, d = t & 63;
        int row = Mtop[bh * NT + u];
        out[((size_t)bh * LL + row) * DD + d] = ctx[((size_t)bh * NT + u) * DD + d];
    }
}

extern "C" void kernel_launch(void* const* d_in, const int* in_sizes, int n_in,
                              void* d_out, int out_size, void* d_ws, size_t ws_size,
                              hipStream_t stream) {
    const float* Q = (const float*)d_in[0];
    const float* K = (const float*)d_in[1];
    const float* V = (const float*)d_in[2];
    const int* isamp = (const int*)d_in[3];
    float* ws   = (float*)d_ws;
    float* M    = ws + WS_M;
    float* sub  = ws + WS_SUB;
    float* ctx  = ws + WS_CTX;
    float* pm   = ws + WS_PM;
    float* psum = ws + WS_PSUM;
    float* pacc = ws + WS_PACC;
    int*   Mtop = (int*)(ws + WS_TOP);
    float* out  = (float*)d_out;

    k1_M      <<<BHN * LL / 4, 256, 0, stream>>>(Q, K, isamp, M);
    k2_topk   <<<BHN,           64, 0, stream>>>(M, Mtop);
    k3a_partial<<<BHN * NCH,   256, 0, stream>>>(Q, K, V, Mtop, pm, psum, pacc);
    k3b_reduce<<<BHN * NT,      64, 0, stream>>>(pm, psum, pacc, ctx);
    k4a_sub   <<<BHN * 64,      64, 0, stream>>>(V, sub);
    k4b_scan  <<<BHN * 64,      64, 0, stream>>>(V, sub, out);
    k5_scatter<<<BHN,          256, 0, stream>>>(Mtop, ctx, out);
}

// Round 4
// 214.898 us; speedup vs baseline: 2.5541x; 1.4191x over previous
//
#include <hip/hip_runtime.h>
#include <hip/hip_bf16.h>
#include <cstdint>

#define BB 4
#define HH 8
#define LL 2048
#define DD 64
#define SK 40
#define NT 40
#define BHN (BB*HH)            // 32
#define SCALE 0.125f
#define CHUNK 128
#define NCH (LL/CHUNK)         // 16

// workspace layout in floats
#define WS_M    0                          // [BHN*LL]            = 65536
#define WS_SUB  (WS_M + BHN*LL)            // [BHN*64*DD]         = 131072
#define WS_CTX  (WS_SUB + BHN*64*DD)       // [BHN*NT*DD]         = 81920
#define WS_PM   (WS_CTX + BHN*NT*DD)       // [BHN*NT*NCH]        = 20480
#define WS_PSUM (WS_PM + BHN*NT*NCH)       // [BHN*NT*NCH]        = 20480
#define WS_PACC (WS_PSUM + BHN*NT*NCH)     // [BHN*NT*NCH*DD]     = 1310720
#define WS_TOP  (WS_PACC + BHN*NT*NCH*DD)  // int [BHN*NT]

// ---------------- K1: M[b,h,l] = max_s(QK) - sum_s(QK)/L ----------------
// One wave per (bh,l) row. 16-lane groups cooperate per sampled K-row so the
// gather is coalesced (4 x float4 per row in one segment), 4 samples/pass,
// 10 passes. Dot via intra-16 shfl_xor; per-lane running max/sum; final
// xor16/32 merge.
__global__ __launch_bounds__(256) void k1_M(const float* __restrict__ Q,
                                            const float* __restrict__ K,
                                            const int* __restrict__ isamp,
                                            float* __restrict__ M) {
    int wid  = blockIdx.x * 4 + (threadIdx.x >> 6);   // = bh*LL + l
    int lane = threadIdx.x & 63;
    int bh   = wid >> 11;
    int l    = wid & (LL - 1);
    int g    = lane >> 4;        // sample group 0..3
    int e    = lane & 15;        // element-quad within row

    // Q row fragment for this lane (same 16 float4 repeated across groups)
    float4 q = reinterpret_cast<const float4*>(Q + (size_t)wid * DD)[e];

    const float* Kbh = K + (size_t)bh * LL * DD;
    const int* irow = isamp + l * SK;

    float mx = -INFINITY, sm = 0.f;
#pragma unroll
    for (int p = 0; p < SK / 4; p++) {
        int s = p * 4 + g;
        int idx = irow[s];                               // broadcast within group
        float4 kv = reinterpret_cast<const float4*>(Kbh + (size_t)idx * DD)[e];
        float d = q.x * kv.x + q.y * kv.y + q.z * kv.z + q.w * kv.w;
        d += __shfl_xor(d, 1);
        d += __shfl_xor(d, 2);
        d += __shfl_xor(d, 4);
        d += __shfl_xor(d, 8);                           // full dot, all lanes of group
        mx = fmaxf(mx, d);
        sm += d;
    }
    // merge the 4 groups
    mx = fmaxf(mx, __shfl_xor(mx, 16));
    mx = fmaxf(mx, __shfl_xor(mx, 32));
    sm += __shfl_xor(sm, 16);
    sm += __shfl_xor(sm, 32);
    if (lane == 0) M[wid] = mx - sm * (1.0f / (float)LL);
}

// ---------------- K2: top-40 indices per (b,h), one wave per bh ----------------
__global__ __launch_bounds__(64) void k2_topk(const float* __restrict__ M,
                                              int* __restrict__ Mtop) {
    __shared__ float m_lds[LL];
    int bh = blockIdx.x, lane = threadIdx.x;
    for (int i = lane; i < LL; i += 64) m_lds[i] = M[bh * LL + i];
    __syncthreads();
    for (int t = 0; t < NT; t++) {
        unsigned long long best = 0ull;
#pragma unroll
        for (int j = 0; j < LL / 64; j++) {
            int i = lane + j * 64;
            float v = m_lds[i];
            unsigned u = __float_as_uint(v);
            u = (u & 0x80000000u) ? ~u : (u | 0x80000000u);
            unsigned long long key = ((unsigned long long)u << 32) | (unsigned)(~i);
            if (key > best) best = key;
        }
#pragma unroll
        for (int off = 32; off; off >>= 1) {
            unsigned long long o = __shfl_xor(best, off);
            if (o > best) best = o;
        }
        int idx = (int)(~(unsigned)(best & 0xFFFFFFFFull));
        if (lane == 0) {
            Mtop[bh * NT + t] = idx;
            m_lds[idx] = -INFINITY;
        }
        __syncthreads();
    }
}

// ---------------- K3a: chunked partial attention ----------------
// block = (bh, chunk); computes masked scores for all 40 u's vs CHUNK keys,
// local softmax stats + partial PV, writes (m, sum, acc[64]) per (bh,u,ch).
__global__ __launch_bounds__(256) void k3a_partial(const float* __restrict__ Q,
                                                   const float* __restrict__ K,
                                                   const float* __restrict__ V,
                                                   const int* __restrict__ Mtop,
                                                   float* __restrict__ pm,
                                                   float* __restrict__ psum,
                                                   float* __restrict__ pacc) {
    __shared__ float q_lds[NT * DD];       // 10 KB
    __shared__ float s_lds[NT][CHUNK];     // 20 KB
    __shared__ int   qi_lds[NT];
    int bh = blockIdx.x / NCH;
    int ch = blockIdx.x % NCH;
    int ck = ch * CHUNK;
    int tid = threadIdx.x;

    if (tid < NT) qi_lds[tid] = Mtop[bh * NT + tid];
    __syncthreads();
    // stage the 40 gathered Q rows (640 float4)
    for (int c = tid; c < NT * 16; c += 256) {
        int u = c >> 4, j = c & 15;
        reinterpret_cast<float4*>(q_lds)[c] =
            reinterpret_cast<const float4*>(Q + ((size_t)bh * LL + qi_lds[u]) * DD)[j];
    }
    __syncthreads();

    // scores: thread pair (half 0/1) per key; K half-row kept in registers
    int k   = ck + (tid >> 1);
    int half = tid & 1;
    const float4* krow = reinterpret_cast<const float4*>(K + ((size_t)bh * LL + k) * DD) + half * 8;
    float4 kreg[8];
#pragma unroll
    for (int j = 0; j < 8; j++) kreg[j] = krow[j];
    for (int u = 0; u < NT; u++) {
        const float4* q4 = reinterpret_cast<const float4*>(q_lds + u * DD) + half * 8;
        float d = 0.f;
#pragma unroll
        for (int j = 0; j < 8; j++) {
            float4 a = q4[j], b = kreg[j];
            d += a.x * b.x + a.y * b.y + a.z * b.z + a.w * b.w;
        }
        d += __shfl_xor(d, 1);
        float s = (k <= qi_lds[u]) ? d * SCALE : -INFINITY;
        if (half == 0) s_lds[u][k - ck] = s;
    }
    __syncthreads();

    // per-u local max + expsum; wave w owns u = w + 4*uu
    int w = tid >> 6, lane = tid & 63;
#pragma unroll
    for (int uu = 0; uu < NT / 4; uu++) {
        int u = w + uu * 4;
        float s0 = s_lds[u][lane], s1 = s_lds[u][lane + 64];
        float m = fmaxf(s0, s1);
#pragma unroll
        for (int off = 32; off; off >>= 1) m = fmaxf(m, __shfl_xor(m, off));
        float e0 = (s0 == -INFINITY) ? 0.f : __expf(s0 - m);
        float e1 = (s1 == -INFINITY) ? 0.f : __expf(s1 - m);
        s_lds[u][lane] = e0;
        s_lds[u][lane + 64] = e1;
        float sm = e0 + e1;
#pragma unroll
        for (int off = 32; off; off >>= 1) sm += __shfl_xor(sm, off);
        if (lane == 0) {
            pm  [((size_t)bh * NT + u) * NCH + ch] = m;
            psum[((size_t)bh * NT + u) * NCH + ch] = sm;
        }
    }
    __syncthreads();

    // partial PV: wave w owns u = w + 4*uu, lane = d; V streamed from global (L2)
    float acc[NT / 4] = {};
    const float* vbase = V + ((size_t)bh * LL + ck) * DD + lane;
#pragma unroll 4
    for (int kk = 0; kk < CHUNK; kk++) {
        float v = vbase[(size_t)kk * DD];
#pragma unroll
        for (int uu = 0; uu < NT / 4; uu++)
            acc[uu] += s_lds[w + uu * 4][kk] * v;
    }
#pragma unroll
    for (int uu = 0; uu < NT / 4; uu++) {
        int u = w + uu * 4;
        pacc[(((size_t)bh * NT + u) * NCH + ch) * DD + lane] = acc[uu];
    }
}

// ---------------- K3b: merge 16 chunk partials per (bh,u) ----------------
__global__ __launch_bounds__(64) void k3b_reduce(const float* __restrict__ pm,
                                                 const float* __restrict__ psum,
                                                 const float* __restrict__ pacc,
                                                 float* __restrict__ ctx) {
    int row = blockIdx.x;            // bh*NT + u
    int lane = threadIdx.x;          // = d
    float pmv[NCH];
    float m = -INFINITY;
#pragma unroll
    for (int i = 0; i < NCH; i++) {
        pmv[i] = pm[(size_t)row * NCH + i];
        m = fmaxf(m, pmv[i]);
    }
    float Z = 0.f, acc = 0.f;
#pragma unroll
    for (int i = 0; i < NCH; i++) {
        float sc = (pmv[i] == -INFINITY) ? 0.f : __expf(pmv[i] - m);
        Z   += psum[(size_t)row * NCH + i] * sc;
        acc += pacc[((size_t)row * NCH + i) * DD + lane] * sc;
    }
    ctx[(size_t)row * DD + lane] = acc / Z;
}

// ---------------- K4a: 32-row sub-chunk sums of V ----------------
__global__ __launch_bounds__(64) void k4a_sub(const float* __restrict__ V,
                                              float* __restrict__ sub) {
    int blk = blockIdx.x;                 // bh*64 + j
    int lane = threadIdx.x;
    size_t base = (size_t)blk * 32 * DD + lane;
    float acc = 0.f;
#pragma unroll 8
    for (int r = 0; r < 32; r++) acc += V[base + (size_t)r * DD];
    sub[(size_t)blk * DD + lane] = acc;
}

// ---------------- K4b: prefix offset + inclusive rescan ----------------
__global__ __launch_bounds__(64) void k4b_scan(const float* __restrict__ V,
                                               const float* __restrict__ sub,
                                               float* __restrict__ out) {
    int blk = blockIdx.x;
    int bh = blk >> 6, j = blk & 63;
    int lane = threadIdx.x;
    float off = 0.f;
    for (int p = 0; p < j; p++) off += sub[((size_t)(bh * 64 + p)) * DD + lane];
    size_t base = (size_t)blk * 32 * DD + lane;
    float acc = off;
    for (int r = 0; r < 32; r++) {
        acc += V[base + (size_t)r * DD];
        out[base + (size_t)r * DD] = acc;
    }
}

// ---------------- K5: scatter ctx_update rows ----------------
__global__ __launch_bounds__(256) void k5_scatter(const int* __restrict__ Mtop,
                                                  const float* __restrict__ ctx,
                                                  float* __restrict__ out) {
    int bh = blockIdx.x, tid = threadIdx.x;
    for (int t = tid; t < NT * DD; t += 256) {
        int u = t >> 6, d = t & 63;
        int row = Mtop[bh * NT + u];
        out[((size_t)bh * LL + row) * DD + d] = ctx[((size_t)bh * NT + u) * DD + d];
    }
}

extern "C" void kernel_launch(void* const* d_in, const int* in_sizes, int n_in,
                              void* d_out, int out_size, void* d_ws, size_t ws_size,
                              hipStream_t stream) {
    const float* Q = (const float*)d_in[0];
    const float* K = (const float*)d_in[1];
    const float* V = (const float*)d_in[2];
    const int* isamp = (const int*)d_in[3];
    float* ws   = (float*)d_ws;
    float* M    = ws + WS_M;
    float* sub  = ws + WS_SUB;
    float* ctx  = ws + WS_CTX;
    float* pm   = ws + WS_PM;
    float* psum = ws + WS_PSUM;
    float* pacc = ws + WS_PACC;
    int*   Mtop = (int*)(ws + WS_TOP);
    float* out  = (float*)d_out;

    k1_M      <<<BHN * LL / 4, 256, 0, stream>>>(Q, K, isamp, M);
    k2_topk   <<<BHN,           64, 0, stream>>>(M, Mtop);
    k3a_partial<<<BHN * NCH,   256, 0, stream>>>(Q, K, V, Mtop, pm, psum, pacc);
    k3b_reduce<<<BHN * NT,      64, 0, stream>>>(pm, psum, pacc, ctx);
    k4a_sub   <<<BHN * 64,      64, 0, stream>>>(V, sub);
    k4b_scan  <<<BHN * 64,      64, 0, stream>>>(V, sub, out);
    k5_scatter<<<BHN,          256, 0, stream>>>(Mtop, ctx, out);
}

// Round 5
// 207.276 us; speedup vs baseline: 2.6480x; 1.0368x over previous
//
#include <hip/hip_runtime.h>
#include <hip/hip_bf16.h>
#include <cstdint>

#define BB 4
#define HH 8
#define LL 2048
#define DD 64
#define SK 40
#define NT 40
#define BHN (BB*HH)            // 32
#define SCALE 0.125f
#define CHUNK 128
#define NCH (LL/CHUNK)         // 16

// workspace layout in floats
#define WS_M    0                          // [BHN*LL]            = 65536
#define WS_SUB  (WS_M + BHN*LL)            // [BHN*64*DD]         = 131072
#define WS_CTX  (WS_SUB + BHN*64*DD)       // [BHN*NT*DD]         (unused now)
#define WS_PM   (WS_CTX + BHN*NT*DD)       // [BHN*NT*NCH]        = 20480
#define WS_PSUM (WS_PM + BHN*NT*NCH)       // [BHN*NT*NCH]        = 20480
#define WS_PACC (WS_PSUM + BHN*NT*NCH)     // [BHN*NT*NCH*DD]     = 1310720
#define WS_TOP  (WS_PACC + BHN*NT*NCH*DD)  // int [BHN*NT]

// ---------------- K1: M[b,h,l] = max_s(QK) - sum_s(QK)/L ----------------
// One wave per (bh,l). 16-lane groups cooperate per sampled K-row (coalesced
// 256B row loads), 4 samples/pass, 10 passes. XCD-swizzled block mapping so
// each XCD owns 4 contiguous bh (K panel 2MB -> L2-resident per XCD).
__global__ __launch_bounds__(256) void k1_M(const float* __restrict__ Q,
                                            const float* __restrict__ K,
                                            const int* __restrict__ isamp,
                                            float* __restrict__ M) {
    int bid  = blockIdx.x;
    int swz  = (bid & 7) * (BHN * LL / 4 / 8) + (bid >> 3);   // 16384%8==0, bijective
    int wid  = swz * 4 + (threadIdx.x >> 6);   // = bh*LL + l
    int lane = threadIdx.x & 63;
    int bh   = wid >> 11;
    int l    = wid & (LL - 1);
    int g    = lane >> 4;        // sample group 0..3
    int e    = lane & 15;        // element-quad within row

    float4 q = reinterpret_cast<const float4*>(Q + (size_t)wid * DD)[e];

    const float* Kbh = K + (size_t)bh * LL * DD;
    const int* irow = isamp + l * SK;

    float mx = -INFINITY, sm = 0.f;
#pragma unroll
    for (int p = 0; p < SK / 4; p++) {
        int s = p * 4 + g;
        int idx = irow[s];                               // broadcast within group
        float4 kv = reinterpret_cast<const float4*>(Kbh + (size_t)idx * DD)[e];
        float d = q.x * kv.x + q.y * kv.y + q.z * kv.z + q.w * kv.w;
        d += __shfl_xor(d, 1);
        d += __shfl_xor(d, 2);
        d += __shfl_xor(d, 4);
        d += __shfl_xor(d, 8);                           // full dot, all lanes of group
        mx = fmaxf(mx, d);
        sm += d;
    }
    mx = fmaxf(mx, __shfl_xor(mx, 16));
    mx = fmaxf(mx, __shfl_xor(mx, 32));
    sm += __shfl_xor(sm, 16);
    sm += __shfl_xor(sm, 32);
    if (lane == 0) M[wid] = mx - sm * (1.0f / (float)LL);
}

// ---------------- K2: top-40 per (b,h); register-resident, one wave ----------------
// 32 packed u64 keys per lane ((monotone(v)<<32)|~idx). Iterative argmax with
// erase-by-value (no runtime register indexing, no LDS, no barriers).
__global__ __launch_bounds__(64) void k2_topk(const float* __restrict__ M,
                                              int* __restrict__ Mtop) {
    int bh = blockIdx.x, lane = threadIdx.x;
    const float* Mb = M + (size_t)bh * LL;
    unsigned long long key[32];
#pragma unroll
    for (int j = 0; j < 32; j++) {
        int i = lane + j * 64;
        unsigned u = __float_as_uint(Mb[i]);
        u = (u & 0x80000000u) ? ~u : (u | 0x80000000u);
        key[j] = ((unsigned long long)u << 32) | (unsigned)(~i);
    }
    unsigned long long winner = 0ull;   // 0 never equals a real key (low word >= 0xFFFFF7FF)
    for (int t = 0; t < NT; t++) {
        unsigned long long best = 0ull;
#pragma unroll
        for (int j = 0; j < 32; j++) {
            unsigned long long k = key[j];
            k = (k == winner) ? 0ull : k;   // erase previous winner
            key[j] = k;
            best = (k > best) ? k : best;
        }
#pragma unroll
        for (int off = 32; off; off >>= 1) {
            unsigned long long o = __shfl_xor(best, off);
            best = (o > best) ? o : best;
        }
        winner = best;
        if (lane == 0) Mtop[bh * NT + t] = (int)(~(unsigned)(best & 0xFFFFFFFFull));
    }
}

// ---------------- K3a: chunked partial attention (XCD-swizzled) ----------------
__global__ __launch_bounds__(256) void k3a_partial(const float* __restrict__ Q,
                                                   const float* __restrict__ K,
                                                   const float* __restrict__ V,
                                                   const int* __restrict__ Mtop,
                                                   float* __restrict__ pm,
                                                   float* __restrict__ psum,
                                                   float* __restrict__ pacc) {
    __shared__ float q_lds[NT * DD];       // 10 KB
    __shared__ float s_lds[NT][CHUNK];     // 20 KB
    __shared__ int   qi_lds[NT];
    int bid = blockIdx.x;
    int swz = (bid & 7) * (BHN * NCH / 8) + (bid >> 3);   // 512%8==0, bijective
    int bh = swz / NCH;
    int ch = swz % NCH;
    int ck = ch * CHUNK;
    int tid = threadIdx.x;

    if (tid < NT) qi_lds[tid] = Mtop[bh * NT + tid];
    __syncthreads();
    for (int c = tid; c < NT * 16; c += 256) {
        int u = c >> 4, j = c & 15;
        reinterpret_cast<float4*>(q_lds)[c] =
            reinterpret_cast<const float4*>(Q + ((size_t)bh * LL + qi_lds[u]) * DD)[j];
    }
    __syncthreads();

    // scores: thread pair (half 0/1) per key; K half-row in registers
    int k   = ck + (tid >> 1);
    int half = tid & 1;
    const float4* krow = reinterpret_cast<const float4*>(K + ((size_t)bh * LL + k) * DD) + half * 8;
    float4 kreg[8];
#pragma unroll
    for (int j = 0; j < 8; j++) kreg[j] = krow[j];
    for (int u = 0; u < NT; u++) {
        const float4* q4 = reinterpret_cast<const float4*>(q_lds + u * DD) + half * 8;
        float d = 0.f;
#pragma unroll
        for (int j = 0; j < 8; j++) {
            float4 a = q4[j], b = kreg[j];
            d += a.x * b.x + a.y * b.y + a.z * b.z + a.w * b.w;
        }
        d += __shfl_xor(d, 1);
        float s = (k <= qi_lds[u]) ? d * SCALE : -INFINITY;
        if (half == 0) s_lds[u][k - ck] = s;
    }
    __syncthreads();

    // per-u local max + expsum; wave w owns u = w + 4*uu
    int w = tid >> 6, lane = tid & 63;
#pragma unroll
    for (int uu = 0; uu < NT / 4; uu++) {
        int u = w + uu * 4;
        float s0 = s_lds[u][lane], s1 = s_lds[u][lane + 64];
        float m = fmaxf(s0, s1);
#pragma unroll
        for (int off = 32; off; off >>= 1) m = fmaxf(m, __shfl_xor(m, off));
        float e0 = (s0 == -INFINITY) ? 0.f : __expf(s0 - m);
        float e1 = (s1 == -INFINITY) ? 0.f : __expf(s1 - m);
        s_lds[u][lane] = e0;
        s_lds[u][lane + 64] = e1;
        float sm = e0 + e1;
#pragma unroll
        for (int off = 32; off; off >>= 1) sm += __shfl_xor(sm, off);
        if (lane == 0) {
            pm  [((size_t)bh * NT + u) * NCH + ch] = m;
            psum[((size_t)bh * NT + u) * NCH + ch] = sm;
        }
    }
    __syncthreads();

    // partial PV: wave w owns u = w + 4*uu, lane = d
    float acc[NT / 4] = {};
    const float* vbase = V + ((size_t)bh * LL + ck) * DD + lane;
#pragma unroll 4
    for (int kk = 0; kk < CHUNK; kk++) {
        float v = vbase[(size_t)kk * DD];
#pragma unroll
        for (int uu = 0; uu < NT / 4; uu++)
            acc[uu] += s_lds[w + uu * 4][kk] * v;
    }
#pragma unroll
    for (int uu = 0; uu < NT / 4; uu++) {
        int u = w + uu * 4;
        pacc[(((size_t)bh * NT + u) * NCH + ch) * DD + lane] = acc[uu];
    }
}

// ---------------- K4a: 32-row sub-chunk sums of V ----------------
__global__ __launch_bounds__(64) void k4a_sub(const float* __restrict__ V,
                                              float* __restrict__ sub) {
    int blk = blockIdx.x;                 // bh*64 + j
    int lane = threadIdx.x;
    size_t base = (size_t)blk * 32 * DD + lane;
    float acc = 0.f;
#pragma unroll 8
    for (int r = 0; r < 32; r++) acc += V[base + (size_t)r * DD];
    sub[(size_t)blk * DD + lane] = acc;
}

// ---------------- K4b: prefix offset + inclusive rescan ----------------
__global__ __launch_bounds__(64) void k4b_scan(const float* __restrict__ V,
                                               const float* __restrict__ sub,
                                               float* __restrict__ out) {
    int blk = blockIdx.x;
    int bh = blk >> 6, j = blk & 63;
    int lane = threadIdx.x;
    float off = 0.f;
    for (int p = 0; p < j; p++) off += sub[((size_t)(bh * 64 + p)) * DD + lane];
    size_t base = (size_t)blk * 32 * DD + lane;
    float acc = off;
    for (int r = 0; r < 32; r++) {
        acc += V[base + (size_t)r * DD];
        out[base + (size_t)r * DD] = acc;
    }
}

// ---------------- K3b': merge chunk partials and scatter directly to out ----------------
// Must run AFTER k4b (overwrites cumsum rows at Mtop positions).
__global__ __launch_bounds__(64) void k3b_scatter(const float* __restrict__ pm,
                                                  const float* __restrict__ psum,
                                                  const float* __restrict__ pacc,
                                                  const int* __restrict__ Mtop,
                                                  float* __restrict__ out) {
    int row = blockIdx.x;            // bh*NT + u
    int lane = threadIdx.x;          // = d
    int bh = row / NT;
    float pmv[NCH];
    float m = -INFINITY;
#pragma unroll
    for (int i = 0; i < NCH; i++) {
        pmv[i] = pm[(size_t)row * NCH + i];
        m = fmaxf(m, pmv[i]);
    }
    float Z = 0.f, acc = 0.f;
#pragma unroll
    for (int i = 0; i < NCH; i++) {
        float sc = (pmv[i] == -INFINITY) ? 0.f : __expf(pmv[i] - m);
        Z   += psum[(size_t)row * NCH + i] * sc;
        acc += pacc[((size_t)row * NCH + i) * DD + lane] * sc;
    }
    int qi = Mtop[row];
    out[((size_t)bh * LL + qi) * DD + lane] = acc / Z;
}

extern "C" void kernel_launch(void* const* d_in, const int* in_sizes, int n_in,
                              void* d_out, int out_size, void* d_ws, size_t ws_size,
                              hipStream_t stream) {
    const float* Q = (const float*)d_in[0];
    const float* K = (const float*)d_in[1];
    const float* V = (const float*)d_in[2];
    const int* isamp = (const int*)d_in[3];
    float* ws   = (float*)d_ws;
    float* M    = ws + WS_M;
    float* sub  = ws + WS_SUB;
    float* pm   = ws + WS_PM;
    float* psum = ws + WS_PSUM;
    float* pacc = ws + WS_PACC;
    int*   Mtop = (int*)(ws + WS_TOP);
    float* out  = (float*)d_out;

    k1_M       <<<BHN * LL / 4, 256, 0, stream>>>(Q, K, isamp, M);
    k2_topk    <<<BHN,           64, 0, stream>>>(M, Mtop);
    k3a_partial<<<BHN * NCH,    256, 0, stream>>>(Q, K, V, Mtop, pm, psum, pacc);
    k4a_sub    <<<BHN * 64,      64, 0, stream>>>(V, sub);
    k4b_scan   <<<BHN * 64,      64, 0, stream>>>(V, sub, out);
    k3b_scatter<<<BHN * NT,      64, 0, stream>>>(pm, psum, pacc, Mtop, out);
}

// Round 6
// 202.730 us; speedup vs baseline: 2.7074x; 1.0224x over previous
//
#include <hip/hip_runtime.h>
#include <hip/hip_bf16.h>
#include <cstdint>

#define BB 4
#define HH 8
#define LL 2048
#define DD 64
#define SK 40
#define NT 40
#define BHN (BB*HH)            // 32
#define SCALE 0.125f
#define CHUNK 128
#define NCH (LL/CHUNK)         // 16
#define USPL 2
#define UPB (NT/USPL)          // 20 u-rows per k3a block

// workspace layout in floats
#define WS_M    0                          // [BHN*LL]            = 65536
#define WS_SUB  (WS_M + BHN*LL)            // [BHN*64*DD]         = 131072
#define WS_CTX  (WS_SUB + BHN*64*DD)       // (unused)
#define WS_PM   (WS_CTX + BHN*NT*DD)       // [BHN*NT*NCH]        = 20480
#define WS_PSUM (WS_PM + BHN*NT*NCH)       // [BHN*NT*NCH]        = 20480
#define WS_PACC (WS_PSUM + BHN*NT*NCH)     // [BHN*NT*NCH*DD]     = 1310720
#define WS_TOP  (WS_PACC + BHN*NT*NCH*DD)  // int [BHN*NT]

// ---------------- K1: M[b,h,l] = max_s(QK) - sum_s(QK)/L ----------------
// One wave per (bh,l). 16-lane groups per sampled K-row (coalesced 256B row
// loads). ILP: all 10 indices loaded upfront, then 2 batches of 5 row-gathers
// in flight before consumption; shfl chains of the 5 samples overlap.
__global__ __launch_bounds__(256) void k1_M(const float* __restrict__ Q,
                                            const float* __restrict__ K,
                                            const int* __restrict__ isamp,
                                            float* __restrict__ M) {
    int bid  = blockIdx.x;
    int swz  = (bid & 7) * (BHN * LL / 4 / 8) + (bid >> 3);   // bijective, 16384%8==0
    int wid  = swz * 4 + (threadIdx.x >> 6);   // = bh*LL + l
    int lane = threadIdx.x & 63;
    int bh   = wid >> 11;
    int l    = wid & (LL - 1);
    int g    = lane >> 4;        // sample group 0..3
    int e    = lane & 15;        // element-quad within row

    float4 q = reinterpret_cast<const float4*>(Q + (size_t)wid * DD)[e];
    const float* Kbh = K + (size_t)bh * LL * DD;
    const int* irow = isamp + l * SK;

    int idxs[SK / 4];
#pragma unroll
    for (int p = 0; p < SK / 4; p++) idxs[p] = irow[p * 4 + g];

    float mx = -INFINITY, sm = 0.f;
#pragma unroll
    for (int b = 0; b < 2; b++) {
        float4 kv[5];
#pragma unroll
        for (int i = 0; i < 5; i++)
            kv[i] = reinterpret_cast<const float4*>(Kbh + (size_t)idxs[b * 5 + i] * DD)[e];
        float dd[5];
#pragma unroll
        for (int i = 0; i < 5; i++)
            dd[i] = q.x * kv[i].x + q.y * kv[i].y + q.z * kv[i].z + q.w * kv[i].w;
#pragma unroll
        for (int i = 0; i < 5; i++) {
            float d = dd[i];
            d += __shfl_xor(d, 1);
            d += __shfl_xor(d, 2);
            d += __shfl_xor(d, 4);
            d += __shfl_xor(d, 8);
            mx = fmaxf(mx, d);
            sm += d;
        }
    }
    mx = fmaxf(mx, __shfl_xor(mx, 16));
    mx = fmaxf(mx, __shfl_xor(mx, 32));
    sm += __shfl_xor(sm, 16);
    sm += __shfl_xor(sm, 32);
    if (lane == 0) M[wid] = mx - sm * (1.0f / (float)LL);
}

// ---------------- K2: top-40 per (b,h); register-resident, one wave ----------------
__global__ __launch_bounds__(64) void k2_topk(const float* __restrict__ M,
                                              int* __restrict__ Mtop) {
    int bh = blockIdx.x, lane = threadIdx.x;
    const float* Mb = M + (size_t)bh * LL;
    unsigned long long key[32];
#pragma unroll
    for (int j = 0; j < 32; j++) {
        int i = lane + j * 64;
        unsigned u = __float_as_uint(Mb[i]);
        u = (u & 0x80000000u) ? ~u : (u | 0x80000000u);
        key[j] = ((unsigned long long)u << 32) | (unsigned)(~i);
    }
    unsigned long long winner = 0ull;
    for (int t = 0; t < NT; t++) {
        unsigned long long best = 0ull;
#pragma unroll
        for (int j = 0; j < 32; j++) {
            unsigned long long k = key[j];
            k = (k == winner) ? 0ull : k;
            key[j] = k;
            best = (k > best) ? k : best;
        }
#pragma unroll
        for (int off = 32; off; off >>= 1) {
            unsigned long long o = __shfl_xor(best, off);
            best = (o > best) ? o : best;
        }
        winner = best;
        if (lane == 0) Mtop[bh * NT + t] = (int)(~(unsigned)(best & 0xFFFFFFFFull));
    }
}

// ---------------- K3a: chunked partial attention, u-split for occupancy ----------------
// block = (bh, chunk, u-half): 20 u-rows x 128 keys. grid 1024, LDS ~15.4KB.
__global__ __launch_bounds__(256) void k3a_partial(const float* __restrict__ Q,
                                                   const float* __restrict__ K,
                                                   const float* __restrict__ V,
                                                   const int* __restrict__ Mtop,
                                                   float* __restrict__ pm,
                                                   float* __restrict__ psum,
                                                   float* __restrict__ pacc) {
    __shared__ float q_lds[UPB * DD];      // 5 KB
    __shared__ float s_lds[UPB][CHUNK];    // 10 KB
    __shared__ int   qi_lds[UPB];
    int bid = blockIdx.x;
    int swz = (bid & 7) * (BHN * NCH * USPL / 8) + (bid >> 3);   // 1024%8==0
    int bh  = swz >> 5;            // / (NCH*USPL)
    int rem = swz & 31;
    int ch  = rem >> 1;
    int u0  = (rem & 1) * UPB;
    int ck  = ch * CHUNK;
    int tid = threadIdx.x;

    if (tid < UPB) qi_lds[tid] = Mtop[bh * NT + u0 + tid];
    __syncthreads();
    for (int c = tid; c < UPB * 16; c += 256) {
        int u = c >> 4, j = c & 15;
        reinterpret_cast<float4*>(q_lds)[c] =
            reinterpret_cast<const float4*>(Q + ((size_t)bh * LL + qi_lds[u]) * DD)[j];
    }
    __syncthreads();

    // scores: thread pair (half 0/1) per key; K half-row in registers
    int k    = ck + (tid >> 1);
    int half = tid & 1;
    const float4* krow = reinterpret_cast<const float4*>(K + ((size_t)bh * LL + k) * DD) + half * 8;
    float4 kreg[8];
#pragma unroll
    for (int j = 0; j < 8; j++) kreg[j] = krow[j];
    for (int u = 0; u < UPB; u++) {
        const float4* q4 = reinterpret_cast<const float4*>(q_lds + u * DD) + half * 8;
        float d = 0.f;
#pragma unroll
        for (int j = 0; j < 8; j++) {
            float4 a = q4[j], b = kreg[j];
            d += a.x * b.x + a.y * b.y + a.z * b.z + a.w * b.w;
        }
        d += __shfl_xor(d, 1);
        float s = (k <= qi_lds[u]) ? d * SCALE : -INFINITY;
        if (half == 0) s_lds[u][k - ck] = s;
    }
    __syncthreads();

    // per-u local max + expsum; wave w owns u = w + 4*uu  (uu < 5)
    int w = tid >> 6, lane = tid & 63;
#pragma unroll
    for (int uu = 0; uu < UPB / 4; uu++) {
        int u = w + uu * 4;
        float s0 = s_lds[u][lane], s1 = s_lds[u][lane + 64];
        float m = fmaxf(s0, s1);
#pragma unroll
        for (int off = 32; off; off >>= 1) m = fmaxf(m, __shfl_xor(m, off));
        float e0 = (s0 == -INFINITY) ? 0.f : __expf(s0 - m);
        float e1 = (s1 == -INFINITY) ? 0.f : __expf(s1 - m);
        s_lds[u][lane] = e0;
        s_lds[u][lane + 64] = e1;
        float smv = e0 + e1;
#pragma unroll
        for (int off = 32; off; off >>= 1) smv += __shfl_xor(smv, off);
        if (lane == 0) {
            size_t rg = (size_t)bh * NT + u0 + u;
            pm  [rg * NCH + ch] = m;
            psum[rg * NCH + ch] = smv;
        }
    }
    __syncthreads();

    // partial PV: wave w owns u = w + 4*uu, lane = d
    float acc[UPB / 4] = {};
    const float* vbase = V + ((size_t)bh * LL + ck) * DD + lane;
#pragma unroll 4
    for (int kk = 0; kk < CHUNK; kk++) {
        float v = vbase[(size_t)kk * DD];
#pragma unroll
        for (int uu = 0; uu < UPB / 4; uu++)
            acc[uu] += s_lds[w + uu * 4][kk] * v;
    }
#pragma unroll
    for (int uu = 0; uu < UPB / 4; uu++) {
        size_t rg = (size_t)bh * NT + u0 + w + uu * 4;
        pacc[(rg * NCH + ch) * DD + lane] = acc[uu];
    }
}

// ---------------- K4a: 32-row sub-chunk sums of V ----------------
__global__ __launch_bounds__(64) void k4a_sub(const float* __restrict__ V,
                                              float* __restrict__ sub) {
    int blk = blockIdx.x;                 // bh*64 + j
    int lane = threadIdx.x;
    size_t base = (size_t)blk * 32 * DD + lane;
    float acc = 0.f;
#pragma unroll 8
    for (int r = 0; r < 32; r++) acc += V[base + (size_t)r * DD];
    sub[(size_t)blk * DD + lane] = acc;
}

// ---------------- K4b: prefix offset + inclusive rescan ----------------
__global__ __launch_bounds__(64) void k4b_scan(const float* __restrict__ V,
                                               const float* __restrict__ sub,
                                               float* __restrict__ out) {
    int blk = blockIdx.x;
    int bh = blk >> 6, j = blk & 63;
    int lane = threadIdx.x;
    float off = 0.f;
    for (int p = 0; p < j; p++) off += sub[((size_t)(bh * 64 + p)) * DD + lane];
    size_t base = (size_t)blk * 32 * DD + lane;
    float acc = off;
    for (int r = 0; r < 32; r++) {
        acc += V[base + (size_t)r * DD];
        out[base + (size_t)r * DD] = acc;
    }
}

// ---------------- K3b': merge chunk partials, scatter to out (after k4b) ----------------
__global__ __launch_bounds__(64) void k3b_scatter(const float* __restrict__ pm,
                                                  const float* __restrict__ psum,
                                                  const float* __restrict__ pacc,
                                                  const int* __restrict__ Mtop,
                                                  float* __restrict__ out) {
    int row = blockIdx.x;            // bh*NT + u
    int lane = threadIdx.x;          // = d
    int bh = row / NT;
    float pmv[NCH];
    float m = -INFINITY;
#pragma unroll
    for (int i = 0; i < NCH; i++) {
        pmv[i] = pm[(size_t)row * NCH + i];
        m = fmaxf(m, pmv[i]);
    }
    float Z = 0.f, acc = 0.f;
#pragma unroll
    for (int i = 0; i < NCH; i++) {
        float sc = (pmv[i] == -INFINITY) ? 0.f : __expf(pmv[i] - m);
        Z   += psum[(size_t)row * NCH + i] * sc;
        acc += pacc[((size_t)row * NCH + i) * DD + lane] * sc;
    }
    int qi = Mtop[row];
    out[((size_t)bh * LL + qi) * DD + lane] = acc / Z;
}

extern "C" void kernel_launch(void* const* d_in, const int* in_sizes, int n_in,
                              void* d_out, int out_size, void* d_ws, size_t ws_size,
                              hipStream_t stream) {
    const float* Q = (const float*)d_in[0];
    const float* K = (const float*)d_in[1];
    const float* V = (const float*)d_in[2];
    const int* isamp = (const int*)d_in[3];
    float* ws   = (float*)d_ws;
    float* M    = ws + WS_M;
    float* sub  = ws + WS_SUB;
    float* pm   = ws + WS_PM;
    float* psum = ws + WS_PSUM;
    float* pacc = ws + WS_PACC;
    int*   Mtop = (int*)(ws + WS_TOP);
    float* out  = (float*)d_out;

    k1_M       <<<BHN * LL / 4,       256, 0, stream>>>(Q, K, isamp, M);
    k2_topk    <<<BHN,                 64, 0, stream>>>(M, Mtop);
    k3a_partial<<<BHN * NCH * USPL,   256, 0, stream>>>(Q, K, V, Mtop, pm, psum, pacc);
    k4a_sub    <<<BHN * 64,            64, 0, stream>>>(V, sub);
    k4b_scan   <<<BHN * 64,            64, 0, stream>>>(V, sub, out);
    k3b_scatter<<<BHN * NT,            64, 0, stream>>>(pm, psum, pacc, Mtop, out);
}